// Round 6
// baseline (352.950 us; speedup 1.0000x reference)
//
#include <hip/hip_runtime.h>
#include <math.h>

#define HOP     128
#define NSLOTS  256
#define FPW     4      // frames per wave (chain length)
#define PI_F    3.14159265358979323846f
#define PI2_F   1.57079632679489661923f
#define K8      0.70710678118654752440f

// Zero-instruction ordering fence for intra-wave LDS cross-lane handoffs:
// "memory" clobber stops LLVM reordering LDS ops across it; DS pipe is
// in-order per wave so no s_waitcnt drain is needed.
#define LDS_FENCE() do { __asm__ volatile("" ::: "memory"); \
                         __builtin_amdgcn_wave_barrier(); } while (0)

struct cpx { float x, y; };
__device__ __forceinline__ cpx cadd(cpx a, cpx b){ return {a.x+b.x, a.y+b.y}; }
__device__ __forceinline__ cpx csub(cpx a, cpx b){ return {a.x-b.x, a.y-b.y}; }
__device__ __forceinline__ cpx cmul(cpx a, cpx b){
    return {fmaf(a.x,b.x,-a.y*b.y), fmaf(a.x,b.y, a.y*b.x)};
}
__device__ __forceinline__ cpx cmulc(cpx a, cpx b){  // a*conj(b)
    return {fmaf(a.x,b.x, a.y*b.y), fmaf(a.y,b.x,-a.x*b.y)};
}

// |atan2(im,re)| in [0,pi] — unchanged from rounds 2-5 (absmax 0.0).
__device__ __forceinline__ float abs_angle(float re, float im) {
    float a = fabsf(im), b = fabsf(re);
    float mn = fminf(a, b), mx = fmaxf(a, b);
    float t = __fdividef(mn, fmaxf(mx, 1e-37f));
    float t2 = t * t;
    float p = fmaf(t2, -0.0117212f, 0.05265332f);
    p = fmaf(t2, p, -0.11643287f);
    p = fmaf(t2, p, 0.19354346f);
    p = fmaf(t2, p, -0.33262347f);
    p = fmaf(t2, p, 0.99997726f);
    float r = t * p;
    r = (a > b) ? (PI2_F - r) : r;
    r = (re < 0.f) ? (PI_F - r) : r;
    return r;
}

// In-register 8-point DFT, natural-order output.
__device__ __forceinline__ void dft8(cpx v[8]) {
    cpx a0=cadd(v[0],v[4]), a1=cadd(v[1],v[5]), a2=cadd(v[2],v[6]), a3=cadd(v[3],v[7]);
    cpx b0=csub(v[0],v[4]), b1=csub(v[1],v[5]), b2=csub(v[2],v[6]), b3=csub(v[3],v[7]);
    b1 = cpx{K8*(b1.x+b1.y), K8*(b1.y-b1.x)};
    b2 = cpx{b2.y, -b2.x};
    b3 = cpx{K8*(b3.y-b3.x), -K8*(b3.x+b3.y)};
    cpx c0=cadd(a0,a2), c2=csub(a0,a2);
    cpx c1=cadd(a1,a3), c3=csub(a1,a3); c3 = cpx{c3.y, -c3.x};
    cpx d0=cadd(b0,b2), d2=csub(b0,b2);
    cpx d1=cadd(b1,b3), d3=csub(b1,b3); d3 = cpx{d3.y, -d3.x};
    v[0]=cadd(c0,c1); v[4]=csub(c0,c1);
    v[2]=cadd(c2,c3); v[6]=csub(c2,c3);
    v[1]=cadd(d0,d1); v[5]=csub(d0,d1);
    v[3]=cadd(d2,d3); v[7]=csub(d2,d3);
}

__global__ __launch_bounds__(256, 8) void phase_loss_kernel(
        const float* __restrict__ y, const float* __restrict__ g,
        float* __restrict__ acc, int* __restrict__ ticket,
        float* __restrict__ out, int T, int n_frames, float inv_count) {
    __shared__ float2 xch_all[4][576];   // per-wave scratch (transpose / Z spectrum)
    __shared__ float wsum[3][4];
    __shared__ int is_last;

    const int tid  = threadIdx.x;
    const int lane = tid & 63;
    const int wid  = tid >> 6;
    float2* xch = xch_all[wid];

    // Per-lane twiddles in registers (k = 1..7), once per kernel.
    cpx tw1[7], tw2[7];
    #pragma unroll
    for (int k = 1; k < 8; ++k) {
        float a1 = -(2.0f * PI_F / 512.0f) * (float)(lane * k);
        __sincosf(a1, &tw1[k-1].y, &tw1[k-1].x);
        float a2 = -(2.0f * PI_F / 64.0f) * (float)((lane & 7) * k);
        __sincosf(a2, &tw2[k-1].y, &tw2[k-1].x);
    }

    float ip = 0.f, gd = 0.f, iaf = 0.f;
    cpx Cp[5];
    const int tmax_int = (T - 256) / HOP;   // frames [2, tmax_int] need no reflect

    auto herm_to_C = [&](float2 zk, float2 zn) -> cpx {
        float ur = zk.x + zn.x, ui = zk.y - zn.y;   // 2*Y
        float vx = zk.x - zn.x, vy = zk.y + zn.y;   // 2i*G
        return cpx{fmaf(ur, vy, -ui * vx),          // C = Y*conj(G), x4 scale
                   fmaf(ur, vx,  ui * vy)};
    };

    auto do_frame = [&](int t, bool accum, bool hp) {
        cpx v[8];
        const int base = t * HOP - 256 + lane;
        if (t >= 2 && t <= tmax_int) {       // fast path: no reflect clamps
            #pragma unroll
            for (int r = 0; r < 8; ++r) {
                int j = base + r * 64;
                v[r].x = y[j]; v[r].y = g[j];
            }
        } else {
            #pragma unroll
            for (int r = 0; r < 8; ++r) {
                int j = base + r * 64;
                j = (j < 0) ? -j : j;
                j = (j >= T) ? (2 * T - 2 - j) : j;
                v[r].x = y[j]; v[r].y = g[j];
            }
        }
        // stage 1: DFT8 over n2, twiddle W512^{lane*k}
        dft8(v);
        #pragma unroll
        for (int k = 1; k < 8; ++k) v[k] = cmul(v[k], tw1[k-1]);
        LDS_FENCE();   // orders prev frame's Z reads vs these writes
        #pragma unroll
        for (int k = 0; k < 8; ++k)
            xch[k * 72 + lane] = make_float2(v[k].x, v[k].y);
        LDS_FENCE();
        {
            const int ra = (lane >> 3) * 72 + (lane & 7);
            #pragma unroll
            for (int r = 0; r < 8; ++r) {
                float2 tmp = xch[ra + r * 8];
                v[r] = cpx{tmp.x, tmp.y};
            }
        }
        // stage 2: DFT8, twiddle W64^{(lane&7)*k}
        dft8(v);
        #pragma unroll
        for (int k = 1; k < 8; ++k) v[k] = cmul(v[k], tw2[k-1]);
        LDS_FENCE();   // WAR: t1 reads before t2 writes (same buffer)
        #pragma unroll
        for (int k = 0; k < 8; ++k)
            xch[k * 65 + lane] = make_float2(v[k].x, v[k].y);
        LDS_FENCE();
        {
            const int ra = (lane >> 3) * 65 + (lane & 7) * 8;
            #pragma unroll
            for (int r = 0; r < 8; ++r) {
                float2 tmp = xch[ra + r];
                v[r] = cpx{tmp.x, tmp.y};
            }
        }
        // stage 3: DFT8 -> bin f = lane + 64*reg; write full spectrum Z to LDS
        dft8(v);
        float2* Z = xch;
        LDS_FENCE();   // WAR: t2 reads before Z writes
        #pragma unroll
        for (int j = 0; j < 8; ++j)
            Z[lane + (j << 6)] = make_float2(v[j].x, v[j].y);
        LDS_FENCE();
        cpx Cc[5];
        #pragma unroll
        for (int jj = 0; jj < 5; ++jj) {
            const int f = lane + (jj << 6);
            Cc[jj] = herm_to_C(make_float2(v[jj].x, v[jj].y),
                               Z[(512 - f) & 511]);
        }
        if (accum) {
            #pragma unroll
            for (int jj = 0; jj < 4; ++jj) {
                const int f = lane + (jj << 6);
                cpx cc = Cc[jj];
                float aw = abs_angle(cc.x, cc.y);
                ip += aw;
                // C[f-1] rebuilt from Z (garbage for f==0, discarded)
                cpx cm = herm_to_C(Z[(f - 1) & 511], Z[(513 - f) & 511]);
                cpx qg = cmulc(cm, cc);
                float gt = abs_angle(qg.x, qg.y);
                gd += (jj == 0 && lane == 0) ? aw : gt;   // gd row 0 == ip term
                if (hp) {
                    cpx qi = cmulc(Cp[jj], cc);
                    iaf += abs_angle(qi.x, qi.y);
                } else {
                    iaf += aw;                             // iaf col 0 == ip term
                }
            }
            if (lane == 0) {   // bin 256
                cpx cc = Cc[4];
                float aw = abs_angle(cc.x, cc.y);
                ip += aw;
                cpx cm = herm_to_C(Z[255], Z[257]);        // C[255]
                cpx qg = cmulc(cm, cc);
                gd += abs_angle(qg.x, qg.y);
                if (hp) {
                    cpx qi = cmulc(Cp[4], cc);
                    iaf += abs_angle(qi.x, qi.y);
                } else {
                    iaf += aw;
                }
            }
        }
        #pragma unroll
        for (int jj = 0; jj < 5; ++jj) Cp[jj] = Cc[jj];
    };

    const int chain   = (blockIdx.x << 2) | wid;        // 0 .. 4*gridDim.x-1
    const int nchains = (int)(gridDim.x << 2);
    const int t0 = chain * FPW;
    int tend = t0 + FPW;
    if (chain == nchains - 1) tend = n_frames;          // last chain takes remainder
    const bool havep = (t0 > 0);

    if (havep) do_frame(t0 - 1, false, false);
    #pragma unroll 2
    for (int t = t0; t < tend; ++t)
        do_frame(t, true, havep || (t > t0));

    // block reduce
    __syncthreads();
    for (int off = 32; off; off >>= 1) {
        ip  += __shfl_down(ip, off);
        gd  += __shfl_down(gd, off);
        iaf += __shfl_down(iaf, off);
    }
    if (lane == 0) { wsum[0][wid] = ip; wsum[1][wid] = gd; wsum[2][wid] = iaf; }
    __syncthreads();
    if (tid == 0) {
        const int slot = (int)(blockIdx.x & (NSLOTS - 1));
        atomicAdd(acc + 0 * NSLOTS + slot, wsum[0][0] + wsum[0][1] + wsum[0][2] + wsum[0][3]);
        atomicAdd(acc + 1 * NSLOTS + slot, wsum[1][0] + wsum[1][1] + wsum[1][2] + wsum[1][3]);
        atomicAdd(acc + 2 * NSLOTS + slot, wsum[2][0] + wsum[2][1] + wsum[2][2] + wsum[2][3]);
        __threadfence();
        is_last = (atomicAdd(ticket, 1) == (int)gridDim.x - 1);
    }
    __syncthreads();
    if (is_last) {
        for (int l = 0; l < 3; l++) {
            float vv = __hip_atomic_load(acc + l * NSLOTS + tid,
                                         __ATOMIC_RELAXED, __HIP_MEMORY_SCOPE_AGENT);
            for (int off = 32; off; off >>= 1) vv += __shfl_down(vv, off);
            if (lane == 0) wsum[l][wid] = vv;
        }
        __syncthreads();
        if (tid < 3)
            out[tid] = (wsum[tid][0] + wsum[tid][1] + wsum[tid][2] + wsum[tid][3]) * inv_count;
    }
}

extern "C" void kernel_launch(void* const* d_in, const int* in_sizes, int n_in,
                              void* d_out, int out_size, void* d_ws, size_t ws_size,
                              hipStream_t stream) {
    const float* y = (const float*)d_in[0];
    const float* g = (const float*)d_in[1];
    float* out = (float*)d_out;
    float* acc = (float*)d_ws;
    int* ticket = (int*)((char*)d_ws + 3 * NSLOTS * sizeof(float));
    const int T = in_sizes[0];
    const int n_frames = T / HOP + 1;                  // 32769
    int n_blocks = n_frames / (FPW * 4);               // 2048 (last chain absorbs rest)
    if (n_blocks < 1) n_blocks = 1;

    hipMemsetAsync(d_ws, 0, 3 * NSLOTS * sizeof(float) + sizeof(int), stream);
    const float inv_count = 1.0f / (257.0f * (float)n_frames);
    phase_loss_kernel<<<n_blocks, 256, 0, stream>>>(y, g, acc, ticket, out,
                                                    T, n_frames, inv_count);
}

// Round 7
// 317.052 us; speedup vs baseline: 1.1132x; 1.1132x over previous
//
#include <hip/hip_runtime.h>
#include <math.h>

#define HOP     128
#define NSLOTS  256
#define FPW     4      // frames per wave (chain length)
#define PI_F    3.14159265358979323846f
#define PI2_F   1.57079632679489661923f
#define K8      0.70710678118654752440f

// Zero-instruction ordering fence for intra-wave LDS cross-lane handoffs:
// "memory" clobber stops LLVM reordering LDS ops across it; DS pipe is
// in-order per wave so no s_waitcnt drain is needed.
#define LDS_FENCE() do { __asm__ volatile("" ::: "memory"); \
                         __builtin_amdgcn_wave_barrier(); } while (0)

struct cpx { float x, y; };
__device__ __forceinline__ cpx cadd(cpx a, cpx b){ return {a.x+b.x, a.y+b.y}; }
__device__ __forceinline__ cpx csub(cpx a, cpx b){ return {a.x-b.x, a.y-b.y}; }
__device__ __forceinline__ cpx cmul(cpx a, cpx b){
    return {fmaf(a.x,b.x,-a.y*b.y), fmaf(a.x,b.y, a.y*b.x)};
}
__device__ __forceinline__ cpx cmulc(cpx a, cpx b){  // a*conj(b)
    return {fmaf(a.x,b.x, a.y*b.y), fmaf(a.y,b.x,-a.x*b.y)};
}

// |atan2(im,re)| in [0,pi] — unchanged from rounds 2-6 (absmax 0.0).
__device__ __forceinline__ float abs_angle(float re, float im) {
    float a = fabsf(im), b = fabsf(re);
    float mn = fminf(a, b), mx = fmaxf(a, b);
    float t = __fdividef(mn, fmaxf(mx, 1e-37f));
    float t2 = t * t;
    float p = fmaf(t2, -0.0117212f, 0.05265332f);
    p = fmaf(t2, p, -0.11643287f);
    p = fmaf(t2, p, 0.19354346f);
    p = fmaf(t2, p, -0.33262347f);
    p = fmaf(t2, p, 0.99997726f);
    float r = t * p;
    r = (a > b) ? (PI2_F - r) : r;
    r = (re < 0.f) ? (PI_F - r) : r;
    return r;
}

// In-register 8-point DFT, natural-order output.
__device__ __forceinline__ void dft8(cpx v[8]) {
    cpx a0=cadd(v[0],v[4]), a1=cadd(v[1],v[5]), a2=cadd(v[2],v[6]), a3=cadd(v[3],v[7]);
    cpx b0=csub(v[0],v[4]), b1=csub(v[1],v[5]), b2=csub(v[2],v[6]), b3=csub(v[3],v[7]);
    b1 = cpx{K8*(b1.x+b1.y), K8*(b1.y-b1.x)};
    b2 = cpx{b2.y, -b2.x};
    b3 = cpx{K8*(b3.y-b3.x), -K8*(b3.x+b3.y)};
    cpx c0=cadd(a0,a2), c2=csub(a0,a2);
    cpx c1=cadd(a1,a3), c3=csub(a1,a3); c3 = cpx{c3.y, -c3.x};
    cpx d0=cadd(b0,b2), d2=csub(b0,b2);
    cpx d1=cadd(b1,b3), d3=csub(b1,b3); d3 = cpx{d3.y, -d3.x};
    v[0]=cadd(c0,c1); v[4]=csub(c0,c1);
    v[2]=cadd(c2,c3); v[6]=csub(c2,c3);
    v[1]=cadd(d0,d1); v[5]=csub(d0,d1);
    v[3]=cadd(d2,d3); v[7]=csub(d2,d3);
}

__global__ __launch_bounds__(256, 6) void phase_loss_kernel(
        const float* __restrict__ y, const float* __restrict__ g,
        float* __restrict__ acc, int* __restrict__ ticket,
        float* __restrict__ out, int T, int n_frames, float inv_count) {
    __shared__ float2 xch_all[4][576];   // per-wave scratch (transpose / Z spectrum)
    __shared__ float wsum[3][4];
    __shared__ int is_last;

    const int tid  = threadIdx.x;
    const int lane = tid & 63;
    const int wid  = tid >> 6;
    float2* xch = xch_all[wid];

    // Per-lane twiddles in registers (k = 1..7), once per kernel.
    cpx tw1[7], tw2[7];
    #pragma unroll
    for (int k = 1; k < 8; ++k) {
        float a1 = -(2.0f * PI_F / 512.0f) * (float)(lane * k);
        __sincosf(a1, &tw1[k-1].y, &tw1[k-1].x);
        float a2 = -(2.0f * PI_F / 64.0f) * (float)((lane & 7) * k);
        __sincosf(a2, &tw2[k-1].y, &tw2[k-1].x);
    }

    float ip = 0.f, gd = 0.f, iaf = 0.f;
    cpx Cp[5];
    const int tmax_int = (T - 256) / HOP;   // frames [2, tmax_int] need no reflect

    auto herm_to_C = [&](float2 zk, float2 zn) -> cpx {
        float ur = zk.x + zn.x, ui = zk.y - zn.y;   // 2*Y
        float vx = zk.x - zn.x, vy = zk.y + zn.y;   // 2i*G
        return cpx{fmaf(ur, vy, -ui * vx),          // C = Y*conj(G), x4 scale
                   fmaf(ur, vx,  ui * vy)};
    };

    auto do_frame = [&](int t, bool accum, bool hp) {
        cpx v[8];
        const int base = t * HOP - 256 + lane;
        if (t >= 2 && t <= tmax_int) {       // fast path: no reflect clamps
            #pragma unroll
            for (int r = 0; r < 8; ++r) {
                int j = base + r * 64;
                v[r].x = y[j]; v[r].y = g[j];
            }
        } else {
            #pragma unroll
            for (int r = 0; r < 8; ++r) {
                int j = base + r * 64;
                j = (j < 0) ? -j : j;
                j = (j >= T) ? (2 * T - 2 - j) : j;
                v[r].x = y[j]; v[r].y = g[j];
            }
        }
        // stage 1: DFT8 over n2, twiddle W512^{lane*k}
        dft8(v);
        #pragma unroll
        for (int k = 1; k < 8; ++k) v[k] = cmul(v[k], tw1[k-1]);
        LDS_FENCE();   // orders prev frame's Z reads vs these writes
        #pragma unroll
        for (int k = 0; k < 8; ++k)
            xch[k * 72 + lane] = make_float2(v[k].x, v[k].y);
        LDS_FENCE();
        {
            const int ra = (lane >> 3) * 72 + (lane & 7);
            #pragma unroll
            for (int r = 0; r < 8; ++r) {
                float2 tmp = xch[ra + r * 8];
                v[r] = cpx{tmp.x, tmp.y};
            }
        }
        // stage 2: DFT8, twiddle W64^{(lane&7)*k}
        dft8(v);
        #pragma unroll
        for (int k = 1; k < 8; ++k) v[k] = cmul(v[k], tw2[k-1]);
        LDS_FENCE();   // WAR: t1 reads before t2 writes (same buffer)
        #pragma unroll
        for (int k = 0; k < 8; ++k)
            xch[k * 65 + lane] = make_float2(v[k].x, v[k].y);
        LDS_FENCE();
        {
            const int ra = (lane >> 3) * 65 + (lane & 7) * 8;
            #pragma unroll
            for (int r = 0; r < 8; ++r) {
                float2 tmp = xch[ra + r];
                v[r] = cpx{tmp.x, tmp.y};
            }
        }
        // stage 3: DFT8 -> bin f = lane + 64*reg; write full spectrum Z to LDS
        dft8(v);
        float2* Z = xch;
        LDS_FENCE();   // WAR: t2 reads before Z writes
        #pragma unroll
        for (int j = 0; j < 8; ++j)
            Z[lane + (j << 6)] = make_float2(v[j].x, v[j].y);
        LDS_FENCE();
        cpx Cc[5];
        #pragma unroll
        for (int jj = 0; jj < 5; ++jj) {
            const int f = lane + (jj << 6);
            Cc[jj] = herm_to_C(make_float2(v[jj].x, v[jj].y),
                               Z[(512 - f) & 511]);
        }
        if (accum) {
            #pragma unroll
            for (int jj = 0; jj < 4; ++jj) {
                const int f = lane + (jj << 6);
                cpx cc = Cc[jj];
                float aw = abs_angle(cc.x, cc.y);
                ip += aw;
                // C[f-1] rebuilt from Z (garbage for f==0, discarded)
                cpx cm = herm_to_C(Z[(f - 1) & 511], Z[(513 - f) & 511]);
                cpx qg = cmulc(cm, cc);
                float gt = abs_angle(qg.x, qg.y);
                gd += (jj == 0 && lane == 0) ? aw : gt;   // gd row 0 == ip term
                if (hp) {
                    cpx qi = cmulc(Cp[jj], cc);
                    iaf += abs_angle(qi.x, qi.y);
                } else {
                    iaf += aw;                             // iaf col 0 == ip term
                }
            }
            if (lane == 0) {   // bin 256
                cpx cc = Cc[4];
                float aw = abs_angle(cc.x, cc.y);
                ip += aw;
                cpx cm = herm_to_C(Z[255], Z[257]);        // C[255]
                cpx qg = cmulc(cm, cc);
                gd += abs_angle(qg.x, qg.y);
                if (hp) {
                    cpx qi = cmulc(Cp[4], cc);
                    iaf += abs_angle(qi.x, qi.y);
                } else {
                    iaf += aw;
                }
            }
        }
        #pragma unroll
        for (int jj = 0; jj < 5; ++jj) Cp[jj] = Cc[jj];
    };

    const int chain   = (blockIdx.x << 2) | wid;        // 0 .. 4*gridDim.x-1
    const int nchains = (int)(gridDim.x << 2);
    const int t0 = chain * FPW;
    int tend = t0 + FPW;
    if (chain == nchains - 1) tend = n_frames;          // last chain takes remainder
    const bool havep = (t0 > 0);

    if (havep) do_frame(t0 - 1, false, false);
    #pragma unroll 2
    for (int t = t0; t < tend; ++t)
        do_frame(t, true, havep || (t > t0));

    // block reduce
    __syncthreads();
    for (int off = 32; off; off >>= 1) {
        ip  += __shfl_down(ip, off);
        gd  += __shfl_down(gd, off);
        iaf += __shfl_down(iaf, off);
    }
    if (lane == 0) { wsum[0][wid] = ip; wsum[1][wid] = gd; wsum[2][wid] = iaf; }
    __syncthreads();
    if (tid == 0) {
        const int slot = (int)(blockIdx.x & (NSLOTS - 1));
        atomicAdd(acc + 0 * NSLOTS + slot, wsum[0][0] + wsum[0][1] + wsum[0][2] + wsum[0][3]);
        atomicAdd(acc + 1 * NSLOTS + slot, wsum[1][0] + wsum[1][1] + wsum[1][2] + wsum[1][3]);
        atomicAdd(acc + 2 * NSLOTS + slot, wsum[2][0] + wsum[2][1] + wsum[2][2] + wsum[2][3]);
        __threadfence();
        is_last = (atomicAdd(ticket, 1) == (int)gridDim.x - 1);
    }
    __syncthreads();
    if (is_last) {
        for (int l = 0; l < 3; l++) {
            float vv = __hip_atomic_load(acc + l * NSLOTS + tid,
                                         __ATOMIC_RELAXED, __HIP_MEMORY_SCOPE_AGENT);
            for (int off = 32; off; off >>= 1) vv += __shfl_down(vv, off);
            if (lane == 0) wsum[l][wid] = vv;
        }
        __syncthreads();
        if (tid < 3)
            out[tid] = (wsum[tid][0] + wsum[tid][1] + wsum[tid][2] + wsum[tid][3]) * inv_count;
    }
}

extern "C" void kernel_launch(void* const* d_in, const int* in_sizes, int n_in,
                              void* d_out, int out_size, void* d_ws, size_t ws_size,
                              hipStream_t stream) {
    const float* y = (const float*)d_in[0];
    const float* g = (const float*)d_in[1];
    float* out = (float*)d_out;
    float* acc = (float*)d_ws;
    int* ticket = (int*)((char*)d_ws + 3 * NSLOTS * sizeof(float));
    const int T = in_sizes[0];
    const int n_frames = T / HOP + 1;                  // 32769
    int n_blocks = n_frames / (FPW * 4);               // 2048 (last chain absorbs rest)
    if (n_blocks < 1) n_blocks = 1;

    hipMemsetAsync(d_ws, 0, 3 * NSLOTS * sizeof(float) + sizeof(int), stream);
    const float inv_count = 1.0f / (257.0f * (float)n_frames);
    phase_loss_kernel<<<n_blocks, 256, 0, stream>>>(y, g, acc, ticket, out,
                                                    T, n_frames, inv_count);
}

// Round 8
// 163.795 us; speedup vs baseline: 2.1548x; 1.9357x over previous
//
#include <hip/hip_runtime.h>
#include <math.h>

#define HOP     128
#define NSLOTS  256
#define FPW     4      // frames per wave (chain length)
#define PI_F    3.14159265358979323846f
#define PI2_F   1.57079632679489661923f
#define K8      0.70710678118654752440f

// Zero-instruction ordering fence for intra-wave LDS cross-lane handoffs:
// "memory" clobber stops LLVM reordering LDS ops across it; DS pipe is
// in-order per wave so no s_waitcnt drain is needed.
#define LDS_FENCE() do { __asm__ volatile("" ::: "memory"); \
                         __builtin_amdgcn_wave_barrier(); } while (0)

struct cpx { float x, y; };
__device__ __forceinline__ cpx cadd(cpx a, cpx b){ return {a.x+b.x, a.y+b.y}; }
__device__ __forceinline__ cpx csub(cpx a, cpx b){ return {a.x-b.x, a.y-b.y}; }
__device__ __forceinline__ cpx cmul(cpx a, cpx b){
    return {fmaf(a.x,b.x,-a.y*b.y), fmaf(a.x,b.y, a.y*b.x)};
}
__device__ __forceinline__ cpx cmulc(cpx a, cpx b){  // a*conj(b)
    return {fmaf(a.x,b.x, a.y*b.y), fmaf(a.y,b.x,-a.x*b.y)};
}

// |atan2(im,re)| in [0,pi] — unchanged from rounds 2-7 (absmax 0.0).
__device__ __forceinline__ float abs_angle(float re, float im) {
    float a = fabsf(im), b = fabsf(re);
    float mn = fminf(a, b), mx = fmaxf(a, b);
    float t = __fdividef(mn, fmaxf(mx, 1e-37f));
    float t2 = t * t;
    float p = fmaf(t2, -0.0117212f, 0.05265332f);
    p = fmaf(t2, p, -0.11643287f);
    p = fmaf(t2, p, 0.19354346f);
    p = fmaf(t2, p, -0.33262347f);
    p = fmaf(t2, p, 0.99997726f);
    float r = t * p;
    r = (a > b) ? (PI2_F - r) : r;
    r = (re < 0.f) ? (PI_F - r) : r;
    return r;
}

// In-register 8-point DFT, natural-order output.
__device__ __forceinline__ void dft8(cpx v[8]) {
    cpx a0=cadd(v[0],v[4]), a1=cadd(v[1],v[5]), a2=cadd(v[2],v[6]), a3=cadd(v[3],v[7]);
    cpx b0=csub(v[0],v[4]), b1=csub(v[1],v[5]), b2=csub(v[2],v[6]), b3=csub(v[3],v[7]);
    b1 = cpx{K8*(b1.x+b1.y), K8*(b1.y-b1.x)};
    b2 = cpx{b2.y, -b2.x};
    b3 = cpx{K8*(b3.y-b3.x), -K8*(b3.x+b3.y)};
    cpx c0=cadd(a0,a2), c2=csub(a0,a2);
    cpx c1=cadd(a1,a3), c3=csub(a1,a3); c3 = cpx{c3.y, -c3.x};
    cpx d0=cadd(b0,b2), d2=csub(b0,b2);
    cpx d1=cadd(b1,b3), d3=csub(b1,b3); d3 = cpx{d3.y, -d3.x};
    v[0]=cadd(c0,c1); v[4]=csub(c0,c1);
    v[2]=cadd(c2,c3); v[6]=csub(c2,c3);
    v[1]=cadd(d0,d1); v[5]=csub(d0,d1);
    v[3]=cadd(d2,d3); v[7]=csub(d2,d3);
}

// (256,4): compiler budgets floor(256/min_waves) VGPRs (measured r6/r7: 8->32,
// 6->40, 4->64). 64 regs is spill-free for this kernel; HW residency then
// allows 8 waves/SIMD (512-reg HW pool) and LDS 18.9KB*8 = 151KB fits.
__global__ __launch_bounds__(256, 4) void phase_loss_kernel(
        const float* __restrict__ y, const float* __restrict__ g,
        float* __restrict__ acc, int* __restrict__ ticket,
        float* __restrict__ out, int T, int n_frames, float inv_count) {
    __shared__ float2 xch_all[4][576];   // per-wave scratch (transpose / Z spectrum)
    __shared__ float wsum[3][4];
    __shared__ int is_last;

    const int tid  = threadIdx.x;
    const int lane = tid & 63;
    const int wid  = tid >> 6;
    float2* xch = xch_all[wid];

    // Per-lane twiddles in registers (k = 1..7), once per kernel.
    cpx tw1[7], tw2[7];
    #pragma unroll
    for (int k = 1; k < 8; ++k) {
        float a1 = -(2.0f * PI_F / 512.0f) * (float)(lane * k);
        __sincosf(a1, &tw1[k-1].y, &tw1[k-1].x);
        float a2 = -(2.0f * PI_F / 64.0f) * (float)((lane & 7) * k);
        __sincosf(a2, &tw2[k-1].y, &tw2[k-1].x);
    }

    float ip = 0.f, gd = 0.f, iaf = 0.f;
    cpx Cp[5];
    const int tmax_int = (T - 256) / HOP;   // frames [2, tmax_int] need no reflect

    auto herm_to_C = [&](float2 zk, float2 zn) -> cpx {
        float ur = zk.x + zn.x, ui = zk.y - zn.y;   // 2*Y
        float vx = zk.x - zn.x, vy = zk.y + zn.y;   // 2i*G
        return cpx{fmaf(ur, vy, -ui * vx),          // C = Y*conj(G), x4 scale
                   fmaf(ur, vx,  ui * vy)};
    };

    auto do_frame = [&](int t, bool accum, bool hp) {
        cpx v[8];
        const int base = t * HOP - 256 + lane;
        if (t >= 2 && t <= tmax_int) {       // fast path: no reflect clamps
            #pragma unroll
            for (int r = 0; r < 8; ++r) {
                int j = base + r * 64;
                v[r].x = y[j]; v[r].y = g[j];
            }
        } else {
            #pragma unroll
            for (int r = 0; r < 8; ++r) {
                int j = base + r * 64;
                j = (j < 0) ? -j : j;
                j = (j >= T) ? (2 * T - 2 - j) : j;
                v[r].x = y[j]; v[r].y = g[j];
            }
        }
        // stage 1: DFT8 over n2, twiddle W512^{lane*k}
        dft8(v);
        #pragma unroll
        for (int k = 1; k < 8; ++k) v[k] = cmul(v[k], tw1[k-1]);
        LDS_FENCE();   // orders prev frame's Z reads vs these writes
        #pragma unroll
        for (int k = 0; k < 8; ++k)
            xch[k * 72 + lane] = make_float2(v[k].x, v[k].y);
        LDS_FENCE();
        {
            const int ra = (lane >> 3) * 72 + (lane & 7);
            #pragma unroll
            for (int r = 0; r < 8; ++r) {
                float2 tmp = xch[ra + r * 8];
                v[r] = cpx{tmp.x, tmp.y};
            }
        }
        // stage 2: DFT8, twiddle W64^{(lane&7)*k}
        dft8(v);
        #pragma unroll
        for (int k = 1; k < 8; ++k) v[k] = cmul(v[k], tw2[k-1]);
        LDS_FENCE();   // WAR: t1 reads before t2 writes (same buffer)
        #pragma unroll
        for (int k = 0; k < 8; ++k)
            xch[k * 65 + lane] = make_float2(v[k].x, v[k].y);
        LDS_FENCE();
        {
            const int ra = (lane >> 3) * 65 + (lane & 7) * 8;
            #pragma unroll
            for (int r = 0; r < 8; ++r) {
                float2 tmp = xch[ra + r];
                v[r] = cpx{tmp.x, tmp.y};
            }
        }
        // stage 3: DFT8 -> bin f = lane + 64*reg; write full spectrum Z to LDS
        dft8(v);
        float2* Z = xch;
        LDS_FENCE();   // WAR: t2 reads before Z writes
        #pragma unroll
        for (int j = 0; j < 8; ++j)
            Z[lane + (j << 6)] = make_float2(v[j].x, v[j].y);
        LDS_FENCE();
        cpx Cc[5];
        #pragma unroll
        for (int jj = 0; jj < 5; ++jj) {
            const int f = lane + (jj << 6);
            Cc[jj] = herm_to_C(make_float2(v[jj].x, v[jj].y),
                               Z[(512 - f) & 511]);
        }
        if (accum) {
            #pragma unroll
            for (int jj = 0; jj < 4; ++jj) {
                const int f = lane + (jj << 6);
                cpx cc = Cc[jj];
                float aw = abs_angle(cc.x, cc.y);
                ip += aw;
                // C[f-1] rebuilt from Z (garbage for f==0, discarded)
                cpx cm = herm_to_C(Z[(f - 1) & 511], Z[(513 - f) & 511]);
                cpx qg = cmulc(cm, cc);
                float gt = abs_angle(qg.x, qg.y);
                gd += (jj == 0 && lane == 0) ? aw : gt;   // gd row 0 == ip term
                if (hp) {
                    cpx qi = cmulc(Cp[jj], cc);
                    iaf += abs_angle(qi.x, qi.y);
                } else {
                    iaf += aw;                             // iaf col 0 == ip term
                }
            }
            if (lane == 0) {   // bin 256
                cpx cc = Cc[4];
                float aw = abs_angle(cc.x, cc.y);
                ip += aw;
                cpx cm = herm_to_C(Z[255], Z[257]);        // C[255]
                cpx qg = cmulc(cm, cc);
                gd += abs_angle(qg.x, qg.y);
                if (hp) {
                    cpx qi = cmulc(Cp[4], cc);
                    iaf += abs_angle(qi.x, qi.y);
                } else {
                    iaf += aw;
                }
            }
        }
        #pragma unroll
        for (int jj = 0; jj < 5; ++jj) Cp[jj] = Cc[jj];
    };

    const int chain   = (blockIdx.x << 2) | wid;        // 0 .. 4*gridDim.x-1
    const int nchains = (int)(gridDim.x << 2);
    const int t0 = chain * FPW;
    int tend = t0 + FPW;
    if (chain == nchains - 1) tend = n_frames;          // last chain takes remainder
    const bool havep = (t0 > 0);

    if (havep) do_frame(t0 - 1, false, false);
    #pragma unroll 2
    for (int t = t0; t < tend; ++t)
        do_frame(t, true, havep || (t > t0));

    // block reduce
    __syncthreads();
    for (int off = 32; off; off >>= 1) {
        ip  += __shfl_down(ip, off);
        gd  += __shfl_down(gd, off);
        iaf += __shfl_down(iaf, off);
    }
    if (lane == 0) { wsum[0][wid] = ip; wsum[1][wid] = gd; wsum[2][wid] = iaf; }
    __syncthreads();
    if (tid == 0) {
        const int slot = (int)(blockIdx.x & (NSLOTS - 1));
        atomicAdd(acc + 0 * NSLOTS + slot, wsum[0][0] + wsum[0][1] + wsum[0][2] + wsum[0][3]);
        atomicAdd(acc + 1 * NSLOTS + slot, wsum[1][0] + wsum[1][1] + wsum[1][2] + wsum[1][3]);
        atomicAdd(acc + 2 * NSLOTS + slot, wsum[2][0] + wsum[2][1] + wsum[2][2] + wsum[2][3]);
        __threadfence();
        is_last = (atomicAdd(ticket, 1) == (int)gridDim.x - 1);
    }
    __syncthreads();
    if (is_last) {
        for (int l = 0; l < 3; l++) {
            float vv = __hip_atomic_load(acc + l * NSLOTS + tid,
                                         __ATOMIC_RELAXED, __HIP_MEMORY_SCOPE_AGENT);
            for (int off = 32; off; off >>= 1) vv += __shfl_down(vv, off);
            if (lane == 0) wsum[l][wid] = vv;
        }
        __syncthreads();
        if (tid < 3)
            out[tid] = (wsum[tid][0] + wsum[tid][1] + wsum[tid][2] + wsum[tid][3]) * inv_count;
    }
}

extern "C" void kernel_launch(void* const* d_in, const int* in_sizes, int n_in,
                              void* d_out, int out_size, void* d_ws, size_t ws_size,
                              hipStream_t stream) {
    const float* y = (const float*)d_in[0];
    const float* g = (const float*)d_in[1];
    float* out = (float*)d_out;
    float* acc = (float*)d_ws;
    int* ticket = (int*)((char*)d_ws + 3 * NSLOTS * sizeof(float));
    const int T = in_sizes[0];
    const int n_frames = T / HOP + 1;                  // 32769
    int n_blocks = n_frames / (FPW * 4);               // 2048 (last chain absorbs rest)
    if (n_blocks < 1) n_blocks = 1;

    hipMemsetAsync(d_ws, 0, 3 * NSLOTS * sizeof(float) + sizeof(int), stream);
    const float inv_count = 1.0f / (257.0f * (float)n_frames);
    phase_loss_kernel<<<n_blocks, 256, 0, stream>>>(y, g, acc, ticket, out,
                                                    T, n_frames, inv_count);
}

// Round 9
// 146.662 us; speedup vs baseline: 2.4065x; 1.1168x over previous
//
#include <hip/hip_runtime.h>
#include <math.h>

#define HOP     128
#define NSLOTS  256
#define FPW     4      // frames per wave (chain length)
#define PI_F    3.14159265358979323846f
#define PI2_F   1.57079632679489661923f
#define K8      0.70710678118654752440f

// Zero-instruction ordering fence for intra-wave LDS cross-lane handoffs:
// "memory" clobber stops LLVM reordering LDS ops across it; DS pipe is
// in-order per wave so no s_waitcnt drain is needed.
#define LDS_FENCE() do { __asm__ volatile("" ::: "memory"); \
                         __builtin_amdgcn_wave_barrier(); } while (0)

struct cpx { float x, y; };
__device__ __forceinline__ cpx cadd(cpx a, cpx b){ return {a.x+b.x, a.y+b.y}; }
__device__ __forceinline__ cpx csub(cpx a, cpx b){ return {a.x-b.x, a.y-b.y}; }
__device__ __forceinline__ cpx cmul(cpx a, cpx b){
    return {fmaf(a.x,b.x,-a.y*b.y), fmaf(a.x,b.y, a.y*b.x)};
}
__device__ __forceinline__ cpx cmulc(cpx a, cpx b){  // a*conj(b)
    return {fmaf(a.x,b.x, a.y*b.y), fmaf(a.y,b.x,-a.x*b.y)};
}

// |atan2(im,re)| in [0,pi] — unchanged from rounds 2-8 (absmax 0.0).
__device__ __forceinline__ float abs_angle(float re, float im) {
    float a = fabsf(im), b = fabsf(re);
    float mn = fminf(a, b), mx = fmaxf(a, b);
    float t = __fdividef(mn, fmaxf(mx, 1e-37f));
    float t2 = t * t;
    float p = fmaf(t2, -0.0117212f, 0.05265332f);
    p = fmaf(t2, p, -0.11643287f);
    p = fmaf(t2, p, 0.19354346f);
    p = fmaf(t2, p, -0.33262347f);
    p = fmaf(t2, p, 0.99997726f);
    float r = t * p;
    r = (a > b) ? (PI2_F - r) : r;
    r = (re < 0.f) ? (PI_F - r) : r;
    return r;
}

// In-register 8-point DFT, natural-order output.
__device__ __forceinline__ void dft8(cpx v[8]) {
    cpx a0=cadd(v[0],v[4]), a1=cadd(v[1],v[5]), a2=cadd(v[2],v[6]), a3=cadd(v[3],v[7]);
    cpx b0=csub(v[0],v[4]), b1=csub(v[1],v[5]), b2=csub(v[2],v[6]), b3=csub(v[3],v[7]);
    b1 = cpx{K8*(b1.x+b1.y), K8*(b1.y-b1.x)};
    b2 = cpx{b2.y, -b2.x};
    b3 = cpx{K8*(b3.y-b3.x), -K8*(b3.x+b3.y)};
    cpx c0=cadd(a0,a2), c2=csub(a0,a2);
    cpx c1=cadd(a1,a3), c3=csub(a1,a3); c3 = cpx{c3.y, -c3.x};
    cpx d0=cadd(b0,b2), d2=csub(b0,b2);
    cpx d1=cadd(b1,b3), d3=csub(b1,b3); d3 = cpx{d3.y, -d3.x};
    v[0]=cadd(c0,c1); v[4]=csub(c0,c1);
    v[2]=cadd(c2,c3); v[6]=csub(c2,c3);
    v[1]=cadd(d0,d1); v[5]=csub(d0,d1);
    v[3]=cadd(d2,d3); v[7]=csub(d2,d3);
}

// (256,4): 64-VGPR compiler budget (measured: min_waves 8/6/4 -> 32/40/64).
// Kernel is trimmed (tw2 in LDS, fused loss loop) to fit 64 spill-free; HW
// residency then gives 8 waves/SIMD (512-reg HW pool), LDS 19KB*8=152KB fits.
__global__ __launch_bounds__(256, 4) void phase_loss_kernel(
        const float* __restrict__ y, const float* __restrict__ g,
        float* __restrict__ acc, int* __restrict__ ticket,
        float* __restrict__ out, int T, int n_frames, float inv_count) {
    __shared__ float2 xch_all[4][576];   // per-wave scratch (transpose / Z spectrum)
    __shared__ float2 tw2_lds[56];       // stage-2 twiddles: [k-1][lane&7]
    __shared__ float wsum[3][4];
    __shared__ int is_last;

    const int tid  = threadIdx.x;
    const int lane = tid & 63;
    const int wid  = tid >> 6;
    float2* xch = xch_all[wid];

    if (tid < 56) {
        int p = tid & 7, kk = tid >> 3;          // kk = k-1
        float ang = -(2.0f * PI_F / 64.0f) * (float)(p * (kk + 1));
        float sn, cs;
        __sincosf(ang, &sn, &cs);
        tw2_lds[tid] = make_float2(cs, sn);
    }

    // Stage-1 twiddles stay in registers (64 lane patterns).
    cpx tw1[7];
    #pragma unroll
    for (int k = 1; k < 8; ++k) {
        float a1 = -(2.0f * PI_F / 512.0f) * (float)(lane * k);
        __sincosf(a1, &tw1[k-1].y, &tw1[k-1].x);
    }
    __syncthreads();   // tw2_lds visible to all waves

    float ip = 0.f, gd = 0.f, iaf = 0.f;
    cpx Cp[5];
    const int tmax_int = (T - 256) / HOP;   // frames [2, tmax_int] need no reflect
    const int l8 = lane & 7;

    auto herm_to_C = [&](float2 zk, float2 zn) -> cpx {
        float ur = zk.x + zn.x, ui = zk.y - zn.y;   // 2*Y
        float vx = zk.x - zn.x, vy = zk.y + zn.y;   // 2i*G
        return cpx{fmaf(ur, vy, -ui * vx),          // C = Y*conj(G), x4 scale
                   fmaf(ur, vx,  ui * vy)};
    };

    auto do_frame = [&](int t, bool accum, bool hp) {
        cpx v[8];
        const int base = t * HOP - 256 + lane;
        if (t >= 2 && t <= tmax_int) {       // fast path: no reflect clamps
            #pragma unroll
            for (int r = 0; r < 8; ++r) {
                int j = base + r * 64;
                v[r].x = y[j]; v[r].y = g[j];
            }
        } else {
            #pragma unroll
            for (int r = 0; r < 8; ++r) {
                int j = base + r * 64;
                j = (j < 0) ? -j : j;
                j = (j >= T) ? (2 * T - 2 - j) : j;
                v[r].x = y[j]; v[r].y = g[j];
            }
        }
        // stage 1: DFT8 over n2, twiddle W512^{lane*k}
        dft8(v);
        #pragma unroll
        for (int k = 1; k < 8; ++k) v[k] = cmul(v[k], tw1[k-1]);
        LDS_FENCE();   // orders prev frame's Z reads vs these writes
        #pragma unroll
        for (int k = 0; k < 8; ++k)
            xch[k * 72 + lane] = make_float2(v[k].x, v[k].y);
        LDS_FENCE();
        {
            const int ra = (lane >> 3) * 72 + l8;
            #pragma unroll
            for (int r = 0; r < 8; ++r) {
                float2 tmp = xch[ra + r * 8];
                v[r] = cpx{tmp.x, tmp.y};
            }
        }
        // stage 2: DFT8, twiddle W64^{(lane&7)*k} from LDS (broadcast reads)
        dft8(v);
        #pragma unroll
        for (int k = 1; k < 8; ++k) {
            float2 t2 = tw2_lds[((k - 1) << 3) + l8];
            v[k] = cmul(v[k], cpx{t2.x, t2.y});
        }
        LDS_FENCE();   // WAR: t1 reads before t2 writes (same buffer)
        #pragma unroll
        for (int k = 0; k < 8; ++k)
            xch[k * 65 + lane] = make_float2(v[k].x, v[k].y);
        LDS_FENCE();
        {
            const int ra = (lane >> 3) * 65 + l8 * 8;
            #pragma unroll
            for (int r = 0; r < 8; ++r) {
                float2 tmp = xch[ra + r];
                v[r] = cpx{tmp.x, tmp.y};
            }
        }
        // stage 3: DFT8 -> bin f = lane + 64*reg; write full spectrum Z to LDS
        dft8(v);
        float2* Z = xch;
        LDS_FENCE();   // WAR: t2 reads before Z writes
        #pragma unroll
        for (int j = 0; j < 8; ++j)
            Z[lane + (j << 6)] = make_float2(v[j].x, v[j].y);
        LDS_FENCE();
        // fused: Hermitian unpack -> C -> losses -> Cp update (no Cc array)
        #pragma unroll
        for (int jj = 0; jj < 5; ++jj) {
            const int f = lane + (jj << 6);
            cpx cc = herm_to_C(make_float2(v[jj].x, v[jj].y),
                               Z[(512 - f) & 511]);
            if (accum && (jj < 4 || lane == 0)) {
                float aw = abs_angle(cc.x, cc.y);
                ip += aw;
                // C[f-1] rebuilt from Z (garbage for f==0, discarded)
                cpx cm = herm_to_C(Z[(f - 1) & 511], Z[(513 - f) & 511]);
                cpx qg = cmulc(cm, cc);
                gd += (f == 0) ? aw : abs_angle(qg.x, qg.y);  // gd row 0 == ip term
                if (hp) {
                    cpx qi = cmulc(Cp[jj], cc);
                    iaf += abs_angle(qi.x, qi.y);
                } else {
                    iaf += aw;                                // iaf col 0 == ip term
                }
            }
            Cp[jj] = cc;
        }
    };

    const int chain   = (blockIdx.x << 2) | wid;        // 0 .. 4*gridDim.x-1
    const int nchains = (int)(gridDim.x << 2);
    const int t0 = chain * FPW;
    int tend = t0 + FPW;
    if (chain == nchains - 1) tend = n_frames;          // last chain takes remainder
    const bool havep = (t0 > 0);

    if (havep) do_frame(t0 - 1, false, false);
    #pragma unroll 1
    for (int t = t0; t < tend; ++t)
        do_frame(t, true, havep || (t > t0));

    // block reduce
    __syncthreads();
    for (int off = 32; off; off >>= 1) {
        ip  += __shfl_down(ip, off);
        gd  += __shfl_down(gd, off);
        iaf += __shfl_down(iaf, off);
    }
    if (lane == 0) { wsum[0][wid] = ip; wsum[1][wid] = gd; wsum[2][wid] = iaf; }
    __syncthreads();
    if (tid == 0) {
        const int slot = (int)(blockIdx.x & (NSLOTS - 1));
        atomicAdd(acc + 0 * NSLOTS + slot, wsum[0][0] + wsum[0][1] + wsum[0][2] + wsum[0][3]);
        atomicAdd(acc + 1 * NSLOTS + slot, wsum[1][0] + wsum[1][1] + wsum[1][2] + wsum[1][3]);
        atomicAdd(acc + 2 * NSLOTS + slot, wsum[2][0] + wsum[2][1] + wsum[2][2] + wsum[2][3]);
        __threadfence();
        is_last = (atomicAdd(ticket, 1) == (int)gridDim.x - 1);
    }
    __syncthreads();
    if (is_last) {
        for (int l = 0; l < 3; l++) {
            float vv = __hip_atomic_load(acc + l * NSLOTS + tid,
                                         __ATOMIC_RELAXED, __HIP_MEMORY_SCOPE_AGENT);
            for (int off = 32; off; off >>= 1) vv += __shfl_down(vv, off);
            if (lane == 0) wsum[l][wid] = vv;
        }
        __syncthreads();
        if (tid < 3)
            out[tid] = (wsum[tid][0] + wsum[tid][1] + wsum[tid][2] + wsum[tid][3]) * inv_count;
    }
}

extern "C" void kernel_launch(void* const* d_in, const int* in_sizes, int n_in,
                              void* d_out, int out_size, void* d_ws, size_t ws_size,
                              hipStream_t stream) {
    const float* y = (const float*)d_in[0];
    const float* g = (const float*)d_in[1];
    float* out = (float*)d_out;
    float* acc = (float*)d_ws;
    int* ticket = (int*)((char*)d_ws + 3 * NSLOTS * sizeof(float));
    const int T = in_sizes[0];
    const int n_frames = T / HOP + 1;                  // 32769
    int n_blocks = n_frames / (FPW * 4);               // 2048 (last chain absorbs rest)
    if (n_blocks < 1) n_blocks = 1;

    hipMemsetAsync(d_ws, 0, 3 * NSLOTS * sizeof(float) + sizeof(int), stream);
    const float inv_count = 1.0f / (257.0f * (float)n_frames);
    phase_loss_kernel<<<n_blocks, 256, 0, stream>>>(y, g, acc, ticket, out,
                                                    T, n_frames, inv_count);
}

// Round 10
// 146.003 us; speedup vs baseline: 2.4174x; 1.0045x over previous
//
#include <hip/hip_runtime.h>
#include <math.h>

#define HOP     128
#define NSLOTS  256
#define FPW     4      // frames per wave (chain length)
#define PI_F    3.14159265358979323846f
#define PI2_F   1.57079632679489661923f
#define K8      0.70710678118654752440f

// Zero-instruction ordering fence for intra-wave LDS cross-lane handoffs.
#define LDS_FENCE() do { __asm__ volatile("" ::: "memory"); \
                         __builtin_amdgcn_wave_barrier(); } while (0)

struct cpx { float x, y; };
__device__ __forceinline__ cpx cadd(cpx a, cpx b){ return {a.x+b.x, a.y+b.y}; }
__device__ __forceinline__ cpx csub(cpx a, cpx b){ return {a.x-b.x, a.y-b.y}; }
__device__ __forceinline__ cpx cmul(cpx a, cpx b){
    return {fmaf(a.x,b.x,-a.y*b.y), fmaf(a.x,b.y, a.y*b.x)};
}
__device__ __forceinline__ cpx cmulc(cpx a, cpx b){  // a*conj(b)
    return {fmaf(a.x,b.x, a.y*b.y), fmaf(a.y,b.x,-a.x*b.y)};
}

// |atan2(im,re)| in [0,pi] — unchanged from rounds 2-9 (absmax 0.0).
__device__ __forceinline__ float abs_angle(float re, float im) {
    float a = fabsf(im), b = fabsf(re);
    float mn = fminf(a, b), mx = fmaxf(a, b);
    float t = __fdividef(mn, fmaxf(mx, 1e-37f));
    float t2 = t * t;
    float p = fmaf(t2, -0.0117212f, 0.05265332f);
    p = fmaf(t2, p, -0.11643287f);
    p = fmaf(t2, p, 0.19354346f);
    p = fmaf(t2, p, -0.33262347f);
    p = fmaf(t2, p, 0.99997726f);
    float r = t * p;
    r = (a > b) ? (PI2_F - r) : r;
    r = (re < 0.f) ? (PI_F - r) : r;
    return r;
}

__device__ __forceinline__ void dft8(cpx v[8]) {
    cpx a0=cadd(v[0],v[4]), a1=cadd(v[1],v[5]), a2=cadd(v[2],v[6]), a3=cadd(v[3],v[7]);
    cpx b0=csub(v[0],v[4]), b1=csub(v[1],v[5]), b2=csub(v[2],v[6]), b3=csub(v[3],v[7]);
    b1 = cpx{K8*(b1.x+b1.y), K8*(b1.y-b1.x)};
    b2 = cpx{b2.y, -b2.x};
    b3 = cpx{K8*(b3.y-b3.x), -K8*(b3.x+b3.y)};
    cpx c0=cadd(a0,a2), c2=csub(a0,a2);
    cpx c1=cadd(a1,a3), c3=csub(a1,a3); c3 = cpx{c3.y, -c3.x};
    cpx d0=cadd(b0,b2), d2=csub(b0,b2);
    cpx d1=cadd(b1,b3), d3=csub(b1,b3); d3 = cpx{d3.y, -d3.x};
    v[0]=cadd(c0,c1); v[4]=csub(c0,c1);
    v[2]=cadd(c2,c3); v[6]=csub(c2,c3);
    v[1]=cadd(d0,d1); v[5]=csub(d0,d1);
    v[3]=cadd(d2,d3); v[7]=csub(d2,d3);
}

// Scheduler co-schedules workgroups against ~64 KB LDS/CU (measured r1-r9:
// occupancy == floor(64KB/LDS_block) across 8.7/18.9/27.1 KB points).
// 272-slot per-wave buffer -> 9.2 KB/block -> 7 blocks = 28 waves/CU.
__global__ __launch_bounds__(256, 4) void phase_loss_kernel(
        const float* __restrict__ y, const float* __restrict__ g,
        float* __restrict__ acc, int* __restrict__ ticket,
        float* __restrict__ out, int T, int n_frames, float inv_count) {
    __shared__ float2 xch_all[4][272];   // per-wave scratch (half-pass transposes / Z halves)
    __shared__ float2 tw2_lds[56];       // stage-2 twiddles: [k-1][lane&7]
    __shared__ float wsum[3][4];
    __shared__ int is_last;

    const int tid  = threadIdx.x;
    const int lane = tid & 63;
    const int wid  = tid >> 6;
    float2* xch = xch_all[wid];

    if (tid < 56) {
        int p = tid & 7, kk = tid >> 3;
        float ang = -(2.0f * PI_F / 64.0f) * (float)(p * (kk + 1));
        float sn, cs;
        __sincosf(ang, &sn, &cs);
        tw2_lds[tid] = make_float2(cs, sn);
    }
    cpx tw1[7];
    #pragma unroll
    for (int k = 1; k < 8; ++k) {
        float a1 = -(2.0f * PI_F / 512.0f) * (float)(lane * k);
        __sincosf(a1, &tw1[k-1].y, &tw1[k-1].x);
    }
    __syncthreads();

    float ip = 0.f, gd = 0.f, iaf = 0.f;
    cpx Cp[5];
    const int tmax_int = (T - 256) / HOP;
    const int l8 = lane & 7;
    const int row = lane >> 3;

    auto herm_to_C = [&](float2 zk, float2 zn) -> cpx {
        float ur = zk.x + zn.x, ui = zk.y - zn.y;   // 2*Y
        float vx = zk.x - zn.x, vy = zk.y + zn.y;   // 2i*G
        return cpx{fmaf(ur, vy, -ui * vx),          // C = Y*conj(G), x4 scale
                   fmaf(ur, vx,  ui * vy)};
    };

    auto do_frame = [&](int t, bool accum, bool hp) {
        cpx v[8];
        const int base = t * HOP - 256 + lane;
        if (t >= 2 && t <= tmax_int) {
            #pragma unroll
            for (int r = 0; r < 8; ++r) {
                int j = base + r * 64;
                v[r].x = y[j]; v[r].y = g[j];
            }
        } else {
            #pragma unroll
            for (int r = 0; r < 8; ++r) {
                int j = base + r * 64;
                j = (j < 0) ? -j : j;
                j = (j >= T) ? (2 * T - 2 - j) : j;
                v[r].x = y[j]; v[r].y = g[j];
            }
        }
        // ---- stage 1 + twiddle ----
        dft8(v);
        #pragma unroll
        for (int k = 1; k < 8; ++k) v[k] = cmul(v[k], tw1[k-1]);
        // ---- transpose 1: half-pass, pitch 68 ----
        cpx u[4];
        LDS_FENCE();   // orders prev frame's reads vs these writes
        #pragma unroll
        for (int k = 0; k < 4; ++k) xch[k * 68 + lane] = make_float2(v[k].x, v[k].y);
        LDS_FENCE();
        if (lane < 32) {
            const int ra = row * 68 + l8;
            #pragma unroll
            for (int r = 0; r < 4; ++r) { float2 w = xch[ra + r * 8];       v[r] = cpx{w.x, w.y}; }
            // v[4..7] still needed for phase B store -> stage into u
            #pragma unroll
            for (int r = 0; r < 4; ++r) { float2 w = xch[ra + (r + 4) * 8]; u[r] = cpx{w.x, w.y}; }
        }
        LDS_FENCE();   // WAR: phase-A reads before overwrite
        #pragma unroll
        for (int k = 0; k < 4; ++k) xch[k * 68 + lane] = make_float2(v[k + 4].x, v[k + 4].y);
        LDS_FENCE();
        if (lane >= 32) {
            const int ra = (row - 4) * 68 + l8;
            #pragma unroll
            for (int r = 0; r < 4; ++r) { float2 w = xch[ra + r * 8];       v[r] = cpx{w.x, w.y}; }
            #pragma unroll
            for (int r = 0; r < 4; ++r) { float2 w = xch[ra + (r + 4) * 8]; u[r] = cpx{w.x, w.y}; }
        }
        #pragma unroll
        for (int r = 0; r < 4; ++r) v[r + 4] = u[r];
        // ---- stage 2 + twiddle (LDS broadcast) ----
        dft8(v);
        #pragma unroll
        for (int k = 1; k < 8; ++k) {
            float2 t2 = tw2_lds[((k - 1) << 3) + l8];
            v[k] = cmul(v[k], cpx{t2.x, t2.y});
        }
        // ---- transpose 2: half-pass, pitch 67 ----
        LDS_FENCE();
        #pragma unroll
        for (int k = 0; k < 4; ++k) xch[k * 67 + lane] = make_float2(v[k].x, v[k].y);
        LDS_FENCE();
        if (lane < 32) {
            const int ra = row * 67 + l8 * 8;
            #pragma unroll
            for (int r = 0; r < 4; ++r) { float2 w = xch[ra + r];     v[r] = cpx{w.x, w.y}; }
            #pragma unroll
            for (int r = 0; r < 4; ++r) { float2 w = xch[ra + r + 4]; u[r] = cpx{w.x, w.y}; }
        }
        LDS_FENCE();
        #pragma unroll
        for (int k = 0; k < 4; ++k) xch[k * 67 + lane] = make_float2(v[k + 4].x, v[k + 4].y);
        LDS_FENCE();
        if (lane >= 32) {
            const int ra = (row - 4) * 67 + l8 * 8;
            #pragma unroll
            for (int r = 0; r < 4; ++r) { float2 w = xch[ra + r];     v[r] = cpx{w.x, w.y}; }
            #pragma unroll
            for (int r = 0; r < 4; ++r) { float2 w = xch[ra + r + 4]; u[r] = cpx{w.x, w.y}; }
        }
        #pragma unroll
        for (int r = 0; r < 4; ++r) v[r + 4] = u[r];
        // ---- stage 3 -> bin f = lane + 64*reg ----
        dft8(v);
        // ---- Z in two halves; losses ----
        LDS_FENCE();
        #pragma unroll
        for (int j = 0; j < 4; ++j) xch[lane + (j << 6)] = make_float2(v[j].x, v[j].y);  // bins 0..255
        LDS_FENCE();
        float2 Q1[4], q255, q257;
        if (accum) {
            Q1[0] = xch[lane ? (lane - 1) : 0];
            #pragma unroll
            for (int j = 1; j < 4; ++j) Q1[j] = xch[lane + (j << 6) - 1];
            if (lane == 0) q255 = xch[255];
        }
        LDS_FENCE();   // WAR
        #pragma unroll
        for (int j = 0; j < 4; ++j) xch[lane + (j << 6)] = make_float2(v[j + 4].x, v[j + 4].y);  // bins 256..511
        LDS_FENCE();
        if (accum && lane == 0) q257 = xch[1];   // Z[257]
        #pragma unroll
        for (int j = 0; j < 4; ++j) {
            const int f = lane + (j << 6);
            float2 zn = xch[256 - f];            // Z[512-f]; f=0 -> garbage, fixed below
            if (j == 0 && lane == 0) zn = make_float2(v[0].x, v[0].y);  // bin0 self-partner
            cpx cc = herm_to_C(make_float2(v[j].x, v[j].y), zn);
            if (accum) {
                float aw = abs_angle(cc.x, cc.y);
                ip += aw;
                float2 q3 = xch[257 - f];        // Z[513-f]; f<=1 fixed below
                if (j == 0 && lane == 1) q3 = Q1[0];   // f=1: Z[512]==Z[0]
                cpx cm = herm_to_C(Q1[j], q3);   // C[f-1]; garbage for f==0, discarded
                cpx qg = cmulc(cm, cc);
                gd += (f == 0) ? aw : abs_angle(qg.x, qg.y);
                if (hp) {
                    cpx qi = cmulc(Cp[j], cc);
                    iaf += abs_angle(qi.x, qi.y);
                } else {
                    iaf += aw;
                }
            }
            Cp[j] = cc;
        }
        {   // bin 256 (lane 0; harmless elsewhere)
            cpx cc = herm_to_C(make_float2(v[4].x, v[4].y), make_float2(v[4].x, v[4].y));
            if (accum && lane == 0) {
                float aw = abs_angle(cc.x, cc.y);
                ip += aw;
                cpx cm = herm_to_C(q255, q257);  // C[255]
                cpx qg = cmulc(cm, cc);
                gd += abs_angle(qg.x, qg.y);
                if (hp) {
                    cpx qi = cmulc(Cp[4], cc);
                    iaf += abs_angle(qi.x, qi.y);
                } else {
                    iaf += aw;
                }
            }
            Cp[4] = cc;
        }
    };

    const int chain   = (blockIdx.x << 2) | wid;
    const int nchains = (int)(gridDim.x << 2);
    const int t0 = chain * FPW;
    int tend = t0 + FPW;
    if (chain == nchains - 1) tend = n_frames;
    const bool havep = (t0 > 0);

    if (havep) do_frame(t0 - 1, false, false);
    #pragma unroll 1
    for (int t = t0; t < tend; ++t)
        do_frame(t, true, havep || (t > t0));

    __syncthreads();
    for (int off = 32; off; off >>= 1) {
        ip  += __shfl_down(ip, off);
        gd  += __shfl_down(gd, off);
        iaf += __shfl_down(iaf, off);
    }
    if (lane == 0) { wsum[0][wid] = ip; wsum[1][wid] = gd; wsum[2][wid] = iaf; }
    __syncthreads();
    if (tid == 0) {
        const int slot = (int)(blockIdx.x & (NSLOTS - 1));
        atomicAdd(acc + 0 * NSLOTS + slot, wsum[0][0] + wsum[0][1] + wsum[0][2] + wsum[0][3]);
        atomicAdd(acc + 1 * NSLOTS + slot, wsum[1][0] + wsum[1][1] + wsum[1][2] + wsum[1][3]);
        atomicAdd(acc + 2 * NSLOTS + slot, wsum[2][0] + wsum[2][1] + wsum[2][2] + wsum[2][3]);
        __threadfence();
        is_last = (atomicAdd(ticket, 1) == (int)gridDim.x - 1);
    }
    __syncthreads();
    if (is_last) {
        for (int l = 0; l < 3; l++) {
            float vv = __hip_atomic_load(acc + l * NSLOTS + tid,
                                         __ATOMIC_RELAXED, __HIP_MEMORY_SCOPE_AGENT);
            for (int off = 32; off; off >>= 1) vv += __shfl_down(vv, off);
            if (lane == 0) wsum[l][wid] = vv;
        }
        __syncthreads();
        if (tid < 3)
            out[tid] = (wsum[tid][0] + wsum[tid][1] + wsum[tid][2] + wsum[tid][3]) * inv_count;
    }
}

extern "C" void kernel_launch(void* const* d_in, const int* in_sizes, int n_in,
                              void* d_out, int out_size, void* d_ws, size_t ws_size,
                              hipStream_t stream) {
    const float* y = (const float*)d_in[0];
    const float* g = (const float*)d_in[1];
    float* out = (float*)d_out;
    float* acc = (float*)d_ws;
    int* ticket = (int*)((char*)d_ws + 3 * NSLOTS * sizeof(float));
    const int T = in_sizes[0];
    const int n_frames = T / HOP + 1;                  // 32769
    int n_blocks = n_frames / (FPW * 4);               // 2048
    if (n_blocks < 1) n_blocks = 1;

    hipMemsetAsync(d_ws, 0, 3 * NSLOTS * sizeof(float) + sizeof(int), stream);
    const float inv_count = 1.0f / (257.0f * (float)n_frames);
    phase_loss_kernel<<<n_blocks, 256, 0, stream>>>(y, g, acc, ticket, out,
                                                    T, n_frames, inv_count);
}